// Round 11
// baseline (572.600 us; speedup 1.0000x reference)
//
#include <hip/hip_runtime.h>
#include <hip/hip_bf16.h>
#include <hip/hip_fp16.h>

// EfficientTransformerEncoder: B=32, D=256, L=1024, NH=8, DH=32, WIN=64, DFF=1024, NL=3.
// Inputs fp32. All bf16 tensors use k-chunk-major layout T[k/8][row][8].
// fp32 accumulate; out fp32.
//
// R1: swapped mfma (mfma(b,a) -> D[n][m]) -> epilogues need no LDS transpose.
// R5: fp16 residual trunk (Xh). R8: XCD-chunked block swizzle on gemm_mfma.
// R9: gemm_mfma LDS-staged via global_load_lds (2-buf + syncthreads), +6%.
// Failed: R2/R3 FFN fusion, R4 QKV+attn fusion, R6 128x256 single-stage,
// R7 gemm_ln M=32, R10 counted-vmcnt 3-buf (occupancy loss > pipeline gain).
// R11 (this): gemm_mfma reverted to R9 exactly; gemm_ln K-loop converted to
// the SAME R9-proven gld_lds staged structure (A 4KB + B 16KB per K-step,
// 20x 1KB segments = 5 gld_lds/wave, double-buffered 40KB LDS). Raises
// outstanding bytes/wave 256B -> 5KB in the grid-limited (2 blocks/CU)
// gemm_ln kernels. Same k-accumulation order -> bit-identical output.
#define BSZ 32
#define DM 256
#define LSEQ 1024
#define MTOK (BSZ * LSEQ)   // 32768 tokens
#define NHEAD 8
#define DHEAD 32
#define WIN 64
#define DFF 1024
#define M8 ((size_t)MTOK * 8)   // chunk stride (shorts) for M-row activations

typedef short bf16x8 __attribute__((ext_vector_type(8)));
typedef float f32x4 __attribute__((ext_vector_type(4)));
typedef unsigned short u16x8 __attribute__((ext_vector_type(8)));
typedef _Float16 f16x4 __attribute__((ext_vector_type(4)));

union BF { __hip_bfloat16 h; unsigned short u; };
__device__ __forceinline__ unsigned short f2bf(float f) { BF b; b.h = __float2bfloat16(f); return b.u; }
__device__ __forceinline__ float bf2f(unsigned short u) { return __uint_as_float((unsigned)u << 16); }

#define GLD_LDS16(gp, lp) __builtin_amdgcn_global_load_lds( \
    (const __attribute__((address_space(1))) void*)(gp),    \
    (__attribute__((address_space(3))) void*)(lp), 16, 0, 0)

// tanh-form GELU (validated round 7)
__device__ __forceinline__ float gelu_fast(float x) {
    float t = x * (0.7978845608f + 0.0356774081f * x * x);
    return x / (1.0f + __expf(-2.0f * t));
}

// ------------------------------------------------------------- weight cvt --
// fp32 [nl][N][K] row-major -> bf16 [nl][K/8][N][8] (k-chunk-major per layer)
__global__ __launch_bounds__(256) void cvt_kernel(
    const float* __restrict__ s, unsigned short* __restrict__ d,
    int N, int K, int nl)
{
    int K8 = K >> 3;
    int per = N * K8;
    int c = blockIdx.x * 256 + threadIdx.x;
    if (c >= per * nl) return;
    int layer = c / per, rem = c - layer * per;
    int n = rem / K8, kc = rem - n * K8;
    const float* sp = s + (size_t)layer * N * K + (size_t)n * K + kc * 8;
    float4 v0 = *(const float4*)sp, v1 = *(const float4*)(sp + 4);
    uint4 o;
    o.x = f2bf(v0.x) | ((unsigned)f2bf(v0.y) << 16);
    o.y = f2bf(v0.z) | ((unsigned)f2bf(v0.w) << 16);
    o.z = f2bf(v1.x) | ((unsigned)f2bf(v1.y) << 16);
    o.w = f2bf(v1.z) | ((unsigned)f2bf(v1.w) << 16);
    *(uint4*)(d + (size_t)layer * N * K + (size_t)kc * N * 8 + (size_t)n * 8) = o;
}

// -------------------------------------------------------------- PE table ---
__global__ __launch_bounds__(256) void pe_kernel(float* __restrict__ PE)
{
    int l = blockIdx.x, c = threadIdx.x;
    int i2 = c & ~1;
    float div = expf(-9.210340371976184f * (float)i2 / 256.0f);  // -ln(10000)
    float ang = (float)l * div;
    PE[l * DM + c] = (c & 1) ? cosf(ang) : sinf(ang);
}

// ---------------------------------------------------------------- embed ----
// Xh row-major fp16 trunk; Xb k-chunk-major bf16.
__global__ __launch_bounds__(256) void embed_kernel(
    const float* __restrict__ F, const float* __restrict__ PE,
    _Float16* __restrict__ Xh, unsigned short* __restrict__ Xb)
{
    __shared__ float tile[64][65];
    int b = blockIdx.z, l0 = blockIdx.y * 64, c0 = blockIdx.x * 64;
    int tid = threadIdx.x;
    int li = tid & 63, c4 = tid >> 6;
    #pragma unroll
    for (int it = 0; it < 16; ++it) {
        int c = c4 + it * 4;
        tile[c][li] = F[((size_t)(b * DM + c0 + c)) * LSEQ + l0 + li];
    }
    __syncthreads();
    // Xh: row-major coalesced (2B per lane, 128B per instr)
    int ci = tid & 63, l4 = tid >> 6;
    #pragma unroll
    for (int it = 0; it < 16; ++it) {
        int l = l4 + it * 4;
        float x = tile[ci][l] + PE[(l0 + l) * DM + c0 + ci];
        Xh[((size_t)b * LSEQ + l0 + l) * DM + c0 + ci] = (_Float16)x;
    }
    // Xb: k-chunk-major, 16B per store, contiguous across 32-lane groups
    int ch = tid >> 5;          // chunk within this c0-range (0..7)
    int lx = tid & 31;
    #pragma unroll
    for (int rd = 0; rd < 2; ++rd) {
        int l = lx + rd * 32;
        unsigned short vs[8];
        #pragma unroll
        for (int e = 0; e < 8; ++e) {
            int c = ch * 8 + e;
            vs[e] = f2bf(tile[c][l] + PE[(l0 + l) * DM + c0 + c]);
        }
        uint4 o;
        o.x = vs[0] | ((unsigned)vs[1] << 16);
        o.y = vs[2] | ((unsigned)vs[3] << 16);
        o.z = vs[4] | ((unsigned)vs[5] << 16);
        o.w = vs[6] | ((unsigned)vs[7] << 16);
        *(uint4*)(Xb + ((size_t)((c0 >> 3) + ch)) * M8 +
                  (size_t)(b * LSEQ + l0 + l) * 8) = o;
    }
}

// --------------------------------------- LDS-staged MFMA gemm (R9 proven) --
// Cb[n-chunk][m][8] = epi( A[kc][m][8] @ Bw[kc][n][8] + bias[n] ).
// Tile 128x128, 4 waves (2x2), BK=32, double-buffered LDS staged via
// global_load_lds (4KB in flight per wave vs 256B register-direct).
// Per K-step: stage next tile (4 gld_lds/wave) || 8 ds_read_b128 + 16 MFMA,
// then one barrier (drains staging). SWAPPED mfma: lane -> (m = i*16+l15,
// n = wn + j*16 + quad*4 + r). Epilogue: pack 4 bf16 -> 8B coalesced store.
// R8 XCD-chunked swizzle retained.
__global__ __launch_bounds__(256) void gemm_mfma_kernel(
    const unsigned short* __restrict__ A, const unsigned short* __restrict__ Bw,
    const float* __restrict__ bias, unsigned short* __restrict__ Cb,
    int M, int N, int K, int gelu)
{
    // [buf][kc(4)][row(128)][8] shorts = 8KB per tile per buf
    __shared__ __align__(16) unsigned short Asm[2][4096];
    __shared__ __align__(16) unsigned short Bsm[2][4096];

    const int tid = threadIdx.x;
    const int lane = tid & 63, wave = tid >> 6;
    const int l15 = lane & 15, quad = lane >> 4;
    const int wm = (wave & 1) * 64, wn = (wave >> 1) * 64;

    // XCD-aware swizzle (bijective when nwg % 8 == 0; identity otherwise)
    const int nbx = gridDim.x, nby = gridDim.y;
    const int nwg = nbx * nby;
    int lin = blockIdx.y * nbx + blockIdx.x;
    int logical = lin;
    if ((nwg & 7) == 0) {
        int cpx = nwg >> 3;
        logical = (lin & 7) * cpx + (lin >> 3);
    }
    const int mi = logical / nby;
    const int ni = logical - mi * nby;
    const int m0 = mi * 128, n0 = ni * 128;

    const size_t Ma8 = (size_t)M * 8, Nb8 = (size_t)N * 8;

    // staging: u = wave*4+s in 0..15; u<8 -> A chunk u>>1 half u&1; else B.
    auto stage = [&](int buf, int t) {
        const size_t kcb = (size_t)t * 4;
        #pragma unroll
        for (int s = 0; s < 4; ++s) {
            const int u = wave * 4 + s;
            const int kc = (u >> 1) & 3;
            const int h = u & 1;
            if (u < 8) {
                GLD_LDS16(A + (kcb + kc) * Ma8 + (size_t)(m0 + h * 64 + lane) * 8,
                          &Asm[buf][kc * 1024 + h * 512 + lane * 8]);
            } else {
                GLD_LDS16(Bw + (kcb + kc) * Nb8 + (size_t)(n0 + h * 64 + lane) * 8,
                          &Bsm[buf][kc * 1024 + h * 512 + lane * 8]);
            }
        }
    };

    f32x4 acc[4][4] = {};
    const int steps = K >> 5;   // 8 for K=256

    stage(0, 0);
    __syncthreads();            // staging(0) complete

    int cur = 0;
    for (int t = 0; t < steps; ++t) {
        if (t + 1 < steps) stage(cur ^ 1, t + 1);   // in flight across compute
        const unsigned short* Ab = &Asm[cur][quad * 1024];
        const unsigned short* Bb = &Bsm[cur][quad * 1024];
        bf16x8 av[4], bv[4];
        #pragma unroll
        for (int i = 0; i < 4; ++i)
            av[i] = *(const bf16x8*)(Ab + (wm + i * 16 + l15) * 8);
        #pragma unroll
        for (int j = 0; j < 4; ++j)
            bv[j] = *(const bf16x8*)(Bb + (wn + j * 16 + l15) * 8);
        #pragma unroll
        for (int i = 0; i < 4; ++i)
            #pragma unroll
            for (int j = 0; j < 4; ++j)
                acc[i][j] = __builtin_amdgcn_mfma_f32_16x16x32_bf16(
                    bv[j], av[i], acc[i][j], 0, 0, 0);
        __syncthreads();        // staging(t+1) done + buf cur free for t+2
        cur ^= 1;
    }

    // epilogue: direct k-chunk-major stores, no transpose.
    float4 bb[4];
    #pragma unroll
    for (int j = 0; j < 4; ++j)
        bb[j] = *(const float4*)(bias + n0 + wn + j * 16 + quad * 4);

    #pragma unroll
    for (int i = 0; i < 4; ++i) {
        const size_t m8 = (size_t)(m0 + wm + i * 16 + l15) * 8;
        #pragma unroll
        for (int j = 0; j < 4; ++j) {
            int nb = n0 + wn + j * 16 + quad * 4;
            float v0 = acc[i][j][0] + bb[j].x;
            float v1 = acc[i][j][1] + bb[j].y;
            float v2 = acc[i][j][2] + bb[j].z;
            float v3 = acc[i][j][3] + bb[j].w;
            if (gelu) {
                v0 = gelu_fast(v0); v1 = gelu_fast(v1);
                v2 = gelu_fast(v2); v3 = gelu_fast(v3);
            }
            uint2 o;
            o.x = f2bf(v0) | ((unsigned)f2bf(v1) << 16);
            o.y = f2bf(v2) | ((unsigned)f2bf(v3) << 16);
            *(uint2*)(Cb + ((size_t)(nb >> 3)) * Ma8 + m8 + (nb & 7)) = o;
        }
    }
}

// ----------------------- LDS-staged MFMA gemm + fused LN (R9 structure) ----
// X = LN( A@Bw^T + bias + resid ) -> Xh (row-major fp16) + Xb (k-chunk bf16).
// N fixed 256; tile M=64 x N=256, 4 waves side-by-side in N. K-loop staged
// via global_load_lds: per K-step A-tile 64x32 (4KB, 4 segs) + B-tile 256x32
// (16KB, 16 segs) = 20x 1KB segments = 5 gld_lds/wave, double-buffered 40KB.
// SWAPPED mfma: lane -> (m = m0+i*16+l15, n = wn+j*16+quad*4+r). Trunk
// in-place safe (per-thread read set == write set).
__global__ __launch_bounds__(256) void gemm_ln_kernel(
    const unsigned short* __restrict__ A, const unsigned short* __restrict__ Bw,
    const float* __restrict__ bias, const _Float16* __restrict__ resid,
    const float* __restrict__ lns, const float* __restrict__ lnb,
    _Float16* __restrict__ Xh, unsigned short* __restrict__ Xb, int K)
{
    __shared__ __align__(16) unsigned short Asm[2][2048];   // [kc4][64][8]  4KB/buf
    __shared__ __align__(16) unsigned short Bsm[2][8192];   // [kc4][256][8] 16KB/buf
    __shared__ float Ss[256], Sq[256];
    const int tid = threadIdx.x;
    const int lane = tid & 63, wave = tid >> 6;
    const int l15 = lane & 15, quad = lane >> 4;
    const int wn = wave * 64;
    const int m0 = blockIdx.x * 64;
    const size_t Nb8 = (size_t)DM * 8;

    // staging: u = wave*5+s in 0..19; u<4 -> A kc=u; else B kc=(u-4)>>2,
    // quarter q=(u-4)&3 (rows q*64..q*64+63). Each segment contiguous 1KB.
    auto stage = [&](int buf, int t) {
        const size_t kcb = (size_t)t * 4;
        #pragma unroll
        for (int s = 0; s < 5; ++s) {
            const int u = wave * 5 + s;
            if (u < 4) {
                GLD_LDS16(A + (kcb + u) * M8 + (size_t)(m0 + lane) * 8,
                          &Asm[buf][u * 512 + lane * 8]);
            } else {
                const int v = u - 4;
                const int kc = v >> 2, q = v & 3;
                GLD_LDS16(Bw + (kcb + kc) * Nb8 + (size_t)(q * 64 + lane) * 8,
                          &Bsm[buf][kc * 2048 + q * 512 + lane * 8]);
            }
        }
    };

    f32x4 acc[4][4] = {};
    const int steps = K >> 5;   // 8 or 32

    stage(0, 0);
    __syncthreads();

    int cur = 0;
    for (int t = 0; t < steps; ++t) {
        if (t + 1 < steps) stage(cur ^ 1, t + 1);
        const unsigned short* Ab = &Asm[cur][quad * 512];
        const unsigned short* Bb = &Bsm[cur][quad * 2048];
        bf16x8 av[4], bv[4];
        #pragma unroll
        for (int i = 0; i < 4; ++i)
            av[i] = *(const bf16x8*)(Ab + (i * 16 + l15) * 8);
        #pragma unroll
        for (int j = 0; j < 4; ++j)
            bv[j] = *(const bf16x8*)(Bb + (wn + j * 16 + l15) * 8);
        #pragma unroll
        for (int i = 0; i < 4; ++i)
            #pragma unroll
            for (int j = 0; j < 4; ++j)
                acc[i][j] = __builtin_amdgcn_mfma_f32_16x16x32_bf16(
                    bv[j], av[i], acc[i][j], 0, 0, 0);
        __syncthreads();
        cur ^= 1;
    }

    // + bias + resid (fp16 trunk: 8B loads)
    float4 bj[4];
    #pragma unroll
    for (int j = 0; j < 4; ++j)
        bj[j] = *(const float4*)(bias + wn + j * 16 + quad * 4);
    #pragma unroll
    for (int i = 0; i < 4; ++i) {
        const _Float16* rp = resid + (size_t)(m0 + i * 16 + l15) * DM + wn + quad * 4;
        #pragma unroll
        for (int j = 0; j < 4; ++j) {
            f16x4 rr = *(const f16x4*)(rp + j * 16);
            acc[i][j][0] += bj[j].x + (float)rr[0];
            acc[i][j][1] += bj[j].y + (float)rr[1];
            acc[i][j][2] += bj[j].z + (float)rr[2];
            acc[i][j][3] += bj[j].w + (float)rr[3];
        }
    }

    // row stats: quad-space reduce (xor 16, 32), then cross-wave via LDS.
    #pragma unroll
    for (int i = 0; i < 4; ++i) {
        float s = 0.f, q = 0.f;
        #pragma unroll
        for (int j = 0; j < 4; ++j)
            #pragma unroll
            for (int r = 0; r < 4; ++r) {
                float x = acc[i][j][r];
                s += x; q = fmaf(x, x, q);
            }
        s += __shfl_xor(s, 16); q += __shfl_xor(q, 16);
        s += __shfl_xor(s, 32); q += __shfl_xor(q, 32);
        if (quad == 0) {
            Ss[wave * 64 + i * 16 + l15] = s;
            Sq[wave * 64 + i * 16 + l15] = q;
        }
    }
    __syncthreads();

    float4 scj[4], bbj[4];
    #pragma unroll
    for (int j = 0; j < 4; ++j) {
        scj[j] = *(const float4*)(lns + wn + j * 16 + quad * 4);
        bbj[j] = *(const float4*)(lnb + wn + j * 16 + quad * 4);
    }
    #pragma unroll
    for (int i = 0; i < 4; ++i) {
        int row = i * 16 + l15;
        float s = Ss[row] + Ss[64 + row] + Ss[128 + row] + Ss[192 + row];
        float q = Sq[row] + Sq[64 + row] + Sq[128 + row] + Sq[192 + row];
        float mean = s * (1.0f / 256.0f);
        float var  = q * (1.0f / 256.0f) - mean * mean;
        float rinv = rsqrtf(var + 1e-5f);
        #pragma unroll
        for (int j = 0; j < 4; ++j) {
            acc[i][j][0] = (acc[i][j][0] - mean) * rinv * scj[j].x + bbj[j].x;
            acc[i][j][1] = (acc[i][j][1] - mean) * rinv * scj[j].y + bbj[j].y;
            acc[i][j][2] = (acc[i][j][2] - mean) * rinv * scj[j].z + bbj[j].z;
            acc[i][j][3] = (acc[i][j][3] - mean) * rinv * scj[j].w + bbj[j].w;
        }
    }

    // stores: Xh fp16 8B; Xb direct k-chunk 8B packs.
    #pragma unroll
    for (int i = 0; i < 4; ++i) {
        int m = m0 + i * 16 + l15;
        size_t gf = (size_t)m * DM + wn + quad * 4;
        size_t m8 = (size_t)m * 8;
        #pragma unroll
        for (int j = 0; j < 4; ++j) {
            f16x4 oh = { (_Float16)acc[i][j][0], (_Float16)acc[i][j][1],
                         (_Float16)acc[i][j][2], (_Float16)acc[i][j][3] };
            *(f16x4*)(Xh + gf + j * 16) = oh;
            int nb = wn + j * 16 + quad * 4;
            uint2 ob;
            ob.x = f2bf(acc[i][j][0]) | ((unsigned)f2bf(acc[i][j][1]) << 16);
            ob.y = f2bf(acc[i][j][2]) | ((unsigned)f2bf(acc[i][j][3]) << 16);
            *(uint2*)(Xb + ((size_t)(nb >> 3)) * M8 + m8 + (nb & 7)) = ob;
        }
    }
}

// ------------------------------------------------------- MFMA attention ----
// QKV/ATT in k-chunk-major layout. One wave per (window, head).
__global__ __launch_bounds__(64) void attn_mfma_kernel(
    const unsigned short* __restrict__ QKV, unsigned short* __restrict__ ATT)
{
    __shared__ __align__(16) char smem[22016];
    unsigned short* Qs = (unsigned short*)smem;           // [dc][t][8] 4x64x8
    unsigned short* Ks = (unsigned short*)(smem + 4096);  // [dc][t][8]
    unsigned short* VT = (unsigned short*)(smem + 8192);  // [d][t] 32 x pitch72
    unsigned short* Ps = (unsigned short*)(smem + 12800); // [q][k] 64 x pitch72
    float*          Po = (float*)(smem + 12800);          // [q][d] 64 x pitch36

    const int wg = blockIdx.x, h = blockIdx.y;
    const int base = wg * WIN;
    const int lane = threadIdx.x;
    const int l15 = lane & 15, quad = lane >> 4;
    const float scale = 0.17677669529663687f;   // 1/sqrt(32)

    // stage Q,K: chunk-major source -> contiguous 1KB per DMA instruction
    #pragma unroll
    for (int dc = 0; dc < 4; ++dc) {
        GLD_LDS16(QKV + ((size_t)(h * 4 + dc)) * M8 + (size_t)(base + lane) * 8,
                  Qs + dc * 512 + (size_t)lane * 8);
        GLD_LDS16(QKV + ((size_t)(32 + h * 4 + dc)) * M8 + (size_t)(base + lane) * 8,
                  Ks + dc * 512 + (size_t)lane * 8);
    }
    u16x8 vv[4];
    #pragma unroll
    for (int cc = 0; cc < 4; ++cc)
        vv[cc] = *(const u16x8*)(QKV + ((size_t)(64 + h * 4 + cc)) * M8 +
                                 (size_t)(base + lane) * 8);
    #pragma unroll
    for (int cc = 0; cc < 4; ++cc)
        #pragma unroll
        for (int e = 0; e < 8; ++e)
            VT[(cc * 8 + e) * 72 + lane] = vv[cc][e];
    __syncthreads();   // drains vmcnt (DMA) + lgkm (VT writes)

    const f32x4 zero4 = {0.f, 0.f, 0.f, 0.f};
    bf16x8 aq[4], bk[4];
    #pragma unroll
    for (int i = 0; i < 4; ++i)
        aq[i] = *(const bf16x8*)(Qs + quad * 512 + (i * 16 + l15) * 8);
    #pragma unroll
    for (int j = 0; j < 4; ++j)
        bk[j] = *(const bf16x8*)(Ks + quad * 512 + (j * 16 + l15) * 8);
    f32x4 S[4][4];
    #pragma unroll
    for (int i = 0; i < 4; ++i)
        #pragma unroll
        for (int j = 0; j < 4; ++j)
            S[i][j] = __builtin_amdgcn_mfma_f32_16x16x32_bf16(aq[i], bk[j], zero4, 0, 0, 0);

    float mx[4][4], sum[4][4];
    #pragma unroll
    for (int i = 0; i < 4; ++i)
        #pragma unroll
        for (int r = 0; r < 4; ++r) {
            float m0 = -1e30f;
            #pragma unroll
            for (int j = 0; j < 4; ++j) {
                S[i][j][r] *= scale;
                m0 = fmaxf(m0, S[i][j][r]);
            }
            mx[i][r] = m0;
        }
    #pragma unroll
    for (int off = 1; off < 16; off <<= 1)
        #pragma unroll
        for (int i = 0; i < 4; ++i)
            #pragma unroll
            for (int r = 0; r < 4; ++r)
                mx[i][r] = fmaxf(mx[i][r], __shfl_xor(mx[i][r], off));
    #pragma unroll
    for (int i = 0; i < 4; ++i)
        #pragma unroll
        for (int r = 0; r < 4; ++r) {
            float s0 = 0.f;
            #pragma unroll
            for (int j = 0; j < 4; ++j) {
                float e = __expf(S[i][j][r] - mx[i][r]);
                S[i][j][r] = e;
                s0 += e;
            }
            sum[i][r] = s0;
        }
    #pragma unroll
    for (int off = 1; off < 16; off <<= 1)
        #pragma unroll
        for (int i = 0; i < 4; ++i)
            #pragma unroll
            for (int r = 0; r < 4; ++r)
                sum[i][r] += __shfl_xor(sum[i][r], off);

    #pragma unroll
    for (int i = 0; i < 4; ++i)
        #pragma unroll
        for (int r = 0; r < 4; ++r) {
            float inv = 1.0f / sum[i][r];
            #pragma unroll
            for (int j = 0; j < 4; ++j)
                Ps[(i * 16 + quad * 4 + r) * 72 + j * 16 + l15] =
                    f2bf(S[i][j][r] * inv);
        }
    asm volatile("s_waitcnt lgkmcnt(0)" ::: "memory");

    bf16x8 ap0[4], ap1[4], bv0[2], bv1[2];
    #pragma unroll
    for (int i = 0; i < 4; ++i) {
        ap0[i] = *(const bf16x8*)(Ps + (i * 16 + l15) * 72 + quad * 8);
        ap1[i] = *(const bf16x8*)(Ps + (i * 16 + l15) * 72 + 32 + quad * 8);
    }
    #pragma unroll
    for (int jd = 0; jd < 2; ++jd) {
        bv0[jd] = *(const bf16x8*)(VT + (jd * 16 + l15) * 72 + quad * 8);
        bv1[jd] = *(const bf16x8*)(VT + (jd * 16 + l15) * 72 + 32 + quad * 8);
    }
    f32x4 O[4][2];
    #pragma unroll
    for (int i = 0; i < 4; ++i)
        #pragma unroll
        for (int jd = 0; jd < 2; ++jd) {
            f32x4 t = __builtin_amdgcn_mfma_f32_16x16x32_bf16(ap0[i], bv0[jd], zero4, 0, 0, 0);
            O[i][jd] = __builtin_amdgcn_mfma_f32_16x16x32_bf16(ap1[i], bv1[jd], t, 0, 0, 0);
        }
    asm volatile("s_waitcnt lgkmcnt(0)" ::: "memory");

    #pragma unroll
    for (int i = 0; i < 4; ++i)
        #pragma unroll
        for (int jd = 0; jd < 2; ++jd)
            #pragma unroll
            for (int r = 0; r < 4; ++r)
                Po[(i * 16 + quad * 4 + r) * 36 + jd * 16 + l15] = O[i][jd][r];
    asm volatile("s_waitcnt lgkmcnt(0)" ::: "memory");

    // ATT out: k-chunk-major, contiguous 1KB per chunk store
    #pragma unroll
    for (int g = 0; g < 4; ++g) {
        f32x4 t0 = *(const f32x4*)(Po + lane * 36 + g * 8);
        f32x4 t1 = *(const f32x4*)(Po + lane * 36 + g * 8 + 4);
        uint4 w;
        w.x = f2bf(t0[0]) | ((unsigned)f2bf(t0[1]) << 16);
        w.y = f2bf(t0[2]) | ((unsigned)f2bf(t0[3]) << 16);
        w.z = f2bf(t1[0]) | ((unsigned)f2bf(t1[1]) << 16);
        w.w = f2bf(t1[2]) | ((unsigned)f2bf(t1[3]) << 16);
        *(uint4*)(ATT + ((size_t)(h * 4 + g)) * M8 + (size_t)(base + lane) * 8) = w;
    }
}

// ---------------------------------------------- final LN + transpose out ---
// single pass: tile 64 tokens x 256 ch in LDS (pitch 257), stats inline.
// reads fp16 trunk, writes fp32 output.
__global__ __launch_bounds__(256) void out_ln_kernel(
    const _Float16* __restrict__ Xh, const float* __restrict__ sc,
    const float* __restrict__ bi, float* __restrict__ out)
{
    __shared__ float tile[64][257];
    __shared__ float mean_s[64], rinv_s[64];
    int b = blockIdx.y, l0 = blockIdx.x * 64;
    int tid = threadIdx.x, wave = tid >> 6, lane = tid & 63;
    int c = lane * 4;
    #pragma unroll
    for (int it = 0; it < 16; ++it) {
        int tl = wave * 16 + it;
        f16x4 h = *(const f16x4*)(Xh + ((size_t)(b * LSEQ + l0 + tl)) * DM + c);
        float vx = (float)h[0], vy = (float)h[1], vz = (float)h[2], vw = (float)h[3];
        tile[tl][c + 0] = vx; tile[tl][c + 1] = vy;
        tile[tl][c + 2] = vz; tile[tl][c + 3] = vw;
        float sm = vx + vy + vz + vw;
        float sq = vx * vx + vy * vy + vz * vz + vw * vw;
        #pragma unroll
        for (int off = 32; off > 0; off >>= 1) {
            sm += __shfl_down(sm, off);
            sq += __shfl_down(sq, off);
        }
        if (lane == 0) {
            float mean = sm * (1.0f / 256.0f);
            float var  = sq * (1.0f / 256.0f) - mean * mean;
            mean_s[tl] = mean;
            rinv_s[tl] = rsqrtf(var + 1e-5f);
        }
    }
    __syncthreads();
    int lout = tid & 63, crow = tid >> 6;
    #pragma unroll
    for (int ct = 0; ct < 4; ++ct) {
        int c0 = ct * 64;
        #pragma unroll
        for (int it = 0; it < 16; ++it) {
            int cc = c0 + crow + it * 4;
            float v = tile[lout][cc];
            out[((size_t)(b * DM + cc)) * LSEQ + l0 + lout] =
                (v - mean_s[lout]) * rinv_s[lout] * sc[cc] + bi[cc];
        }
    }
}

// ----------------------------------------------------------------- driver --
extern "C" void kernel_launch(void* const* d_in, const int* in_sizes, int n_in,
                              void* d_out, int out_size, void* d_ws, size_t ws_size,
                              hipStream_t stream)
{
    const float* F   = (const float*)d_in[0];
    const float* Wi  = (const float*)d_in[1];
    const float* Bi  = (const float*)d_in[2];
    const float* Wo  = (const float*)d_in[3];
    const float* Bo  = (const float*)d_in[4];
    const float* W1  = (const float*)d_in[5];
    const float* B1  = (const float*)d_in[6];
    const float* W2  = (const float*)d_in[7];
    const float* B2  = (const float*)d_in[8];
    const float* L1s = (const float*)d_in[9];
    const float* L1b = (const float*)d_in[10];
    const float* L2s = (const float*)d_in[11];
    const float* L2b = (const float*)d_in[12];
    const float* Fs  = (const float*)d_in[13];
    const float* Fb  = (const float*)d_in[14];

    char* w = (char*)d_ws;
    _Float16*       Xh   = (_Float16*)w;                           // 16.8 MB
    unsigned short* QKVb = (unsigned short*)(w + 33554432);        // 50 MB
    unsigned short* Hb   = (unsigned short*)(w + 83886080);        // 67 MB
    unsigned short* Xb   = (unsigned short*)(w + 150994944);       // 16.8 MB
    unsigned short* ATTb = (unsigned short*)(w + 167772160);       // 16.8 MB
    unsigned short* WB   = (unsigned short*)(w + 184549376);       // 4.7 MB
    float*          PE   = (float*)(w + 189267968);                // 1 MB
    unsigned short* Wib  = WB;
    unsigned short* Wob  = WB + 589824;
    unsigned short* W1b  = WB + 786432;
    unsigned short* W2b  = WB + 1572864;

    cvt_kernel<<<(3 * 768 * 32 + 255) / 256, 256, 0, stream>>>(Wi, Wib, 768, 256, 3);
    cvt_kernel<<<(3 * 256 * 32 + 255) / 256, 256, 0, stream>>>(Wo, Wob, 256, 256, 3);
    cvt_kernel<<<(3 * 1024 * 32 + 255) / 256, 256, 0, stream>>>(W1, W1b, 1024, 256, 3);
    cvt_kernel<<<(3 * 256 * 128 + 255) / 256, 256, 0, stream>>>(W2, W2b, 256, 1024, 3);
    pe_kernel<<<LSEQ, 256, 0, stream>>>(PE);
    embed_kernel<<<dim3(DM / 64, LSEQ / 64, BSZ), 256, 0, stream>>>(F, PE, Xh, Xb);

    for (int i = 0; i < 3; ++i) {
        // QKV = X @ Wi^T + bi -> QKVb (k-chunk bf16)
        gemm_mfma_kernel<<<dim3(MTOK / 128, 768 / 128), 256, 0, stream>>>(
            Xb, Wib + (size_t)i * 196608, Bi + i * 768, QKVb, MTOK, 768, DM, 0);
        // windowed MHA -> ATTb
        attn_mfma_kernel<<<dim3(BSZ * (LSEQ / WIN), NHEAD), 64, 0, stream>>>(QKVb, ATTb);
        // X = LN1( ATT @ Wo^T + bo + X ) -> Xh + Xb
        gemm_ln_kernel<<<MTOK / 64, 256, 0, stream>>>(
            ATTb, Wob + (size_t)i * 65536, Bo + i * DM, Xh,
            L1s + i * DM, L1b + i * DM, Xh, Xb, DM);
        // H = GELU(X @ W1^T + b1) -> Hb
        gemm_mfma_kernel<<<dim3(MTOK / 128, DFF / 128), 256, 0, stream>>>(
            Xb, W1b + (size_t)i * 262144, B1 + i * DFF, Hb, MTOK, DFF, DM, 1);
        // X = LN2( H @ W2^T + b2 + X ) -> Xh + Xb
        gemm_ln_kernel<<<MTOK / 64, 256, 0, stream>>>(
            Hb, W2b + (size_t)i * 262144, B2 + i * DM, Xh,
            L2s + i * DM, L2b + i * DM, Xh, Xb, DFF);
    }

    out_ln_kernel<<<dim3(LSEQ / 64, BSZ), 256, 0, stream>>>(
        Xh, Fs, Fb, (float*)d_out);
}

// Round 12
// 527.409 us; speedup vs baseline: 1.0857x; 1.0857x over previous
//
#include <hip/hip_runtime.h>
#include <hip/hip_bf16.h>
#include <hip/hip_fp16.h>

// EfficientTransformerEncoder: B=32, D=256, L=1024, NH=8, DH=32, WIN=64, DFF=1024, NL=3.
// Inputs fp32. All bf16 tensors use k-chunk-major layout T[k/8][row][8].
// fp32 accumulate; out fp32.
//
// R1: swapped mfma (mfma(b,a) -> D[n][m]) -> epilogues need no LDS transpose.
// R5: fp16 residual trunk (Xh). R8: XCD-chunked block swizzle on gemm_mfma.
// R9: gemm_mfma LDS-staged via global_load_lds (2-buf + syncthreads), +6%.
// Failed: R2/R3 FFN fusion, R4 QKV+attn fusion, R6 128x256 single-stage,
// R7 gemm_ln M=32, R10 counted-vmcnt 3-buf, R11 staged gemm_ln (grid-limited
// 2 blocks/CU cannot cover per-K-step barriers -> register-direct wins there).
// RULE: gld_lds staging pays at >=4-5 resident blocks/CU; barrier-free
// register-direct wins when grid-limited.
// R12 (this): gemm_ln reverted to R9 register-direct. Attention LDS compacted
// 22016 -> 13824 B by overlaying Ps/Po onto the dead Qs/Ks region (Qs/Ks are
// consumed into registers before Ps is written; same-wave DS ops execute in
// program order). Residency 7 -> 11 blocks/CU on the latency-bound 1-wave
// attention kernel.
#define BSZ 32
#define DM 256
#define LSEQ 1024
#define MTOK (BSZ * LSEQ)   // 32768 tokens
#define NHEAD 8
#define DHEAD 32
#define WIN 64
#define DFF 1024
#define M8 ((size_t)MTOK * 8)   // chunk stride (shorts) for M-row activations

typedef short bf16x8 __attribute__((ext_vector_type(8)));
typedef float f32x4 __attribute__((ext_vector_type(4)));
typedef unsigned short u16x8 __attribute__((ext_vector_type(8)));
typedef _Float16 f16x4 __attribute__((ext_vector_type(4)));

union BF { __hip_bfloat16 h; unsigned short u; };
__device__ __forceinline__ unsigned short f2bf(float f) { BF b; b.h = __float2bfloat16(f); return b.u; }
__device__ __forceinline__ float bf2f(unsigned short u) { return __uint_as_float((unsigned)u << 16); }

#define GLD_LDS16(gp, lp) __builtin_amdgcn_global_load_lds( \
    (const __attribute__((address_space(1))) void*)(gp),    \
    (__attribute__((address_space(3))) void*)(lp), 16, 0, 0)

// tanh-form GELU (validated round 7)
__device__ __forceinline__ float gelu_fast(float x) {
    float t = x * (0.7978845608f + 0.0356774081f * x * x);
    return x / (1.0f + __expf(-2.0f * t));
}

// ------------------------------------------------------------- weight cvt --
// fp32 [nl][N][K] row-major -> bf16 [nl][K/8][N][8] (k-chunk-major per layer)
__global__ __launch_bounds__(256) void cvt_kernel(
    const float* __restrict__ s, unsigned short* __restrict__ d,
    int N, int K, int nl)
{
    int K8 = K >> 3;
    int per = N * K8;
    int c = blockIdx.x * 256 + threadIdx.x;
    if (c >= per * nl) return;
    int layer = c / per, rem = c - layer * per;
    int n = rem / K8, kc = rem - n * K8;
    const float* sp = s + (size_t)layer * N * K + (size_t)n * K + kc * 8;
    float4 v0 = *(const float4*)sp, v1 = *(const float4*)(sp + 4);
    uint4 o;
    o.x = f2bf(v0.x) | ((unsigned)f2bf(v0.y) << 16);
    o.y = f2bf(v0.z) | ((unsigned)f2bf(v0.w) << 16);
    o.z = f2bf(v1.x) | ((unsigned)f2bf(v1.y) << 16);
    o.w = f2bf(v1.z) | ((unsigned)f2bf(v1.w) << 16);
    *(uint4*)(d + (size_t)layer * N * K + (size_t)kc * N * 8 + (size_t)n * 8) = o;
}

// -------------------------------------------------------------- PE table ---
__global__ __launch_bounds__(256) void pe_kernel(float* __restrict__ PE)
{
    int l = blockIdx.x, c = threadIdx.x;
    int i2 = c & ~1;
    float div = expf(-9.210340371976184f * (float)i2 / 256.0f);  // -ln(10000)
    float ang = (float)l * div;
    PE[l * DM + c] = (c & 1) ? cosf(ang) : sinf(ang);
}

// ---------------------------------------------------------------- embed ----
// Xh row-major fp16 trunk; Xb k-chunk-major bf16.
__global__ __launch_bounds__(256) void embed_kernel(
    const float* __restrict__ F, const float* __restrict__ PE,
    _Float16* __restrict__ Xh, unsigned short* __restrict__ Xb)
{
    __shared__ float tile[64][65];
    int b = blockIdx.z, l0 = blockIdx.y * 64, c0 = blockIdx.x * 64;
    int tid = threadIdx.x;
    int li = tid & 63, c4 = tid >> 6;
    #pragma unroll
    for (int it = 0; it < 16; ++it) {
        int c = c4 + it * 4;
        tile[c][li] = F[((size_t)(b * DM + c0 + c)) * LSEQ + l0 + li];
    }
    __syncthreads();
    // Xh: row-major coalesced (2B per lane, 128B per instr)
    int ci = tid & 63, l4 = tid >> 6;
    #pragma unroll
    for (int it = 0; it < 16; ++it) {
        int l = l4 + it * 4;
        float x = tile[ci][l] + PE[(l0 + l) * DM + c0 + ci];
        Xh[((size_t)b * LSEQ + l0 + l) * DM + c0 + ci] = (_Float16)x;
    }
    // Xb: k-chunk-major, 16B per store, contiguous across 32-lane groups
    int ch = tid >> 5;          // chunk within this c0-range (0..7)
    int lx = tid & 31;
    #pragma unroll
    for (int rd = 0; rd < 2; ++rd) {
        int l = lx + rd * 32;
        unsigned short vs[8];
        #pragma unroll
        for (int e = 0; e < 8; ++e) {
            int c = ch * 8 + e;
            vs[e] = f2bf(tile[c][l] + PE[(l0 + l) * DM + c0 + c]);
        }
        uint4 o;
        o.x = vs[0] | ((unsigned)vs[1] << 16);
        o.y = vs[2] | ((unsigned)vs[3] << 16);
        o.z = vs[4] | ((unsigned)vs[5] << 16);
        o.w = vs[6] | ((unsigned)vs[7] << 16);
        *(uint4*)(Xb + ((size_t)((c0 >> 3) + ch)) * M8 +
                  (size_t)(b * LSEQ + l0 + l) * 8) = o;
    }
}

// --------------------------------------- LDS-staged MFMA gemm (R9 proven) --
// Cb[n-chunk][m][8] = epi( A[kc][m][8] @ Bw[kc][n][8] + bias[n] ).
// Tile 128x128, 4 waves (2x2), BK=32, double-buffered LDS staged via
// global_load_lds (4KB in flight per wave vs 256B register-direct).
// Per K-step: stage next tile (4 gld_lds/wave) || 8 ds_read_b128 + 16 MFMA,
// then one barrier (drains staging). SWAPPED mfma: lane -> (m = i*16+l15,
// n = wn + j*16 + quad*4 + r). Epilogue: pack 4 bf16 -> 8B coalesced store.
// R8 XCD-chunked swizzle retained.
__global__ __launch_bounds__(256) void gemm_mfma_kernel(
    const unsigned short* __restrict__ A, const unsigned short* __restrict__ Bw,
    const float* __restrict__ bias, unsigned short* __restrict__ Cb,
    int M, int N, int K, int gelu)
{
    // [buf][kc(4)][row(128)][8] shorts = 8KB per tile per buf
    __shared__ __align__(16) unsigned short Asm[2][4096];
    __shared__ __align__(16) unsigned short Bsm[2][4096];

    const int tid = threadIdx.x;
    const int lane = tid & 63, wave = tid >> 6;
    const int l15 = lane & 15, quad = lane >> 4;
    const int wm = (wave & 1) * 64, wn = (wave >> 1) * 64;

    // XCD-aware swizzle (bijective when nwg % 8 == 0; identity otherwise)
    const int nbx = gridDim.x, nby = gridDim.y;
    const int nwg = nbx * nby;
    int lin = blockIdx.y * nbx + blockIdx.x;
    int logical = lin;
    if ((nwg & 7) == 0) {
        int cpx = nwg >> 3;
        logical = (lin & 7) * cpx + (lin >> 3);
    }
    const int mi = logical / nby;
    const int ni = logical - mi * nby;
    const int m0 = mi * 128, n0 = ni * 128;

    const size_t Ma8 = (size_t)M * 8, Nb8 = (size_t)N * 8;

    // staging: u = wave*4+s in 0..15; u<8 -> A chunk u>>1 half u&1; else B.
    auto stage = [&](int buf, int t) {
        const size_t kcb = (size_t)t * 4;
        #pragma unroll
        for (int s = 0; s < 4; ++s) {
            const int u = wave * 4 + s;
            const int kc = (u >> 1) & 3;
            const int h = u & 1;
            if (u < 8) {
                GLD_LDS16(A + (kcb + kc) * Ma8 + (size_t)(m0 + h * 64 + lane) * 8,
                          &Asm[buf][kc * 1024 + h * 512 + lane * 8]);
            } else {
                GLD_LDS16(Bw + (kcb + kc) * Nb8 + (size_t)(n0 + h * 64 + lane) * 8,
                          &Bsm[buf][kc * 1024 + h * 512 + lane * 8]);
            }
        }
    };

    f32x4 acc[4][4] = {};
    const int steps = K >> 5;   // 8 for K=256

    stage(0, 0);
    __syncthreads();            // staging(0) complete

    int cur = 0;
    for (int t = 0; t < steps; ++t) {
        if (t + 1 < steps) stage(cur ^ 1, t + 1);   // in flight across compute
        const unsigned short* Ab = &Asm[cur][quad * 1024];
        const unsigned short* Bb = &Bsm[cur][quad * 1024];
        bf16x8 av[4], bv[4];
        #pragma unroll
        for (int i = 0; i < 4; ++i)
            av[i] = *(const bf16x8*)(Ab + (wm + i * 16 + l15) * 8);
        #pragma unroll
        for (int j = 0; j < 4; ++j)
            bv[j] = *(const bf16x8*)(Bb + (wn + j * 16 + l15) * 8);
        #pragma unroll
        for (int i = 0; i < 4; ++i)
            #pragma unroll
            for (int j = 0; j < 4; ++j)
                acc[i][j] = __builtin_amdgcn_mfma_f32_16x16x32_bf16(
                    bv[j], av[i], acc[i][j], 0, 0, 0);
        __syncthreads();        // staging(t+1) done + buf cur free for t+2
        cur ^= 1;
    }

    // epilogue: direct k-chunk-major stores, no transpose.
    float4 bb[4];
    #pragma unroll
    for (int j = 0; j < 4; ++j)
        bb[j] = *(const float4*)(bias + n0 + wn + j * 16 + quad * 4);

    #pragma unroll
    for (int i = 0; i < 4; ++i) {
        const size_t m8 = (size_t)(m0 + wm + i * 16 + l15) * 8;
        #pragma unroll
        for (int j = 0; j < 4; ++j) {
            int nb = n0 + wn + j * 16 + quad * 4;
            float v0 = acc[i][j][0] + bb[j].x;
            float v1 = acc[i][j][1] + bb[j].y;
            float v2 = acc[i][j][2] + bb[j].z;
            float v3 = acc[i][j][3] + bb[j].w;
            if (gelu) {
                v0 = gelu_fast(v0); v1 = gelu_fast(v1);
                v2 = gelu_fast(v2); v3 = gelu_fast(v3);
            }
            uint2 o;
            o.x = f2bf(v0) | ((unsigned)f2bf(v1) << 16);
            o.y = f2bf(v2) | ((unsigned)f2bf(v3) << 16);
            *(uint2*)(Cb + ((size_t)(nb >> 3)) * Ma8 + m8 + (nb & 7)) = o;
        }
    }
}

// --------------------------------- register-direct MFMA gemm + fused LN ----
// X = LN( A@Bw^T + bias + resid ) -> Xh (row-major fp16) + Xb (k-chunk bf16).
// N fixed 256; tile M=64 x N=256, 4 waves side-by-side in N. SWAPPED mfma:
// lane -> (m = m0+i*16+l15, n = wn+j*16+quad*4+r). Trunk in-place is safe:
// each thread reads exactly the resid cells it later overwrites.
// Register-direct (barrier-free) is PROVEN best here: grid 512 = 2 blocks/CU
// cannot cover per-K-step barriers (R11 staged variant regressed).
__global__ __launch_bounds__(256) void gemm_ln_kernel(
    const unsigned short* __restrict__ A, const unsigned short* __restrict__ Bw,
    const float* __restrict__ bias, const _Float16* __restrict__ resid,
    const float* __restrict__ lns, const float* __restrict__ lnb,
    _Float16* __restrict__ Xh, unsigned short* __restrict__ Xb, int K)
{
    __shared__ float Ss[256], Sq[256];
    const int tid = threadIdx.x;
    const int lane = tid & 63, wave = tid >> 6;
    const int l15 = lane & 15, quad = lane >> 4;
    const int wn = wave * 64;
    const int m0 = blockIdx.x * 64;
    const size_t Nb8 = (size_t)DM * 8;
    const size_t astep = 4 * M8, bstep = 4 * Nb8;

    const unsigned short* ap[4];
    const unsigned short* bp[4];
    #pragma unroll
    for (int i = 0; i < 4; ++i)
        ap[i] = A + quad * M8 + (size_t)(m0 + i * 16 + l15) * 8;
    #pragma unroll
    for (int j = 0; j < 4; ++j)
        bp[j] = Bw + quad * Nb8 + (size_t)(wn + j * 16 + l15) * 8;

    f32x4 acc[4][4] = {};
    bf16x8 aA[4], bA[4], aB[4], bB[4];
    #pragma unroll
    for (int i = 0; i < 4; ++i) aA[i] = *(const bf16x8*)(ap[i]);
    #pragma unroll
    for (int j = 0; j < 4; ++j) bA[j] = *(const bf16x8*)(bp[j]);

    const int iters = K >> 5;
    for (int t = 0; t < iters; t += 2) {
        size_t o1 = (size_t)(t + 1);
        #pragma unroll
        for (int i = 0; i < 4; ++i) aB[i] = *(const bf16x8*)(ap[i] + o1 * astep);
        #pragma unroll
        for (int j = 0; j < 4; ++j) bB[j] = *(const bf16x8*)(bp[j] + o1 * bstep);
        #pragma unroll
        for (int i = 0; i < 4; ++i)
            #pragma unroll
            for (int j = 0; j < 4; ++j)
                acc[i][j] = __builtin_amdgcn_mfma_f32_16x16x32_bf16(
                    bA[j], aA[i], acc[i][j], 0, 0, 0);
        size_t o2 = (size_t)((t + 2 < iters) ? t + 2 : iters - 1);
        #pragma unroll
        for (int i = 0; i < 4; ++i) aA[i] = *(const bf16x8*)(ap[i] + o2 * astep);
        #pragma unroll
        for (int j = 0; j < 4; ++j) bA[j] = *(const bf16x8*)(bp[j] + o2 * bstep);
        #pragma unroll
        for (int i = 0; i < 4; ++i)
            #pragma unroll
            for (int j = 0; j < 4; ++j)
                acc[i][j] = __builtin_amdgcn_mfma_f32_16x16x32_bf16(
                    bB[j], aB[i], acc[i][j], 0, 0, 0);
    }

    // + bias + resid (fp16 trunk: 8B loads)
    float4 bj[4];
    #pragma unroll
    for (int j = 0; j < 4; ++j)
        bj[j] = *(const float4*)(bias + wn + j * 16 + quad * 4);
    #pragma unroll
    for (int i = 0; i < 4; ++i) {
        const _Float16* rp = resid + (size_t)(m0 + i * 16 + l15) * DM + wn + quad * 4;
        #pragma unroll
        for (int j = 0; j < 4; ++j) {
            f16x4 rr = *(const f16x4*)(rp + j * 16);
            acc[i][j][0] += bj[j].x + (float)rr[0];
            acc[i][j][1] += bj[j].y + (float)rr[1];
            acc[i][j][2] += bj[j].z + (float)rr[2];
            acc[i][j][3] += bj[j].w + (float)rr[3];
        }
    }

    // row stats: quad-space reduce (xor 16, 32), then cross-wave via LDS.
    #pragma unroll
    for (int i = 0; i < 4; ++i) {
        float s = 0.f, q = 0.f;
        #pragma unroll
        for (int j = 0; j < 4; ++j)
            #pragma unroll
            for (int r = 0; r < 4; ++r) {
                float x = acc[i][j][r];
                s += x; q = fmaf(x, x, q);
            }
        s += __shfl_xor(s, 16); q += __shfl_xor(q, 16);
        s += __shfl_xor(s, 32); q += __shfl_xor(q, 32);
        if (quad == 0) {
            Ss[wave * 64 + i * 16 + l15] = s;
            Sq[wave * 64 + i * 16 + l15] = q;
        }
    }
    __syncthreads();

    float4 scj[4], bbj[4];
    #pragma unroll
    for (int j = 0; j < 4; ++j) {
        scj[j] = *(const float4*)(lns + wn + j * 16 + quad * 4);
        bbj[j] = *(const float4*)(lnb + wn + j * 16 + quad * 4);
    }
    #pragma unroll
    for (int i = 0; i < 4; ++i) {
        int row = i * 16 + l15;
        float s = Ss[row] + Ss[64 + row] + Ss[128 + row] + Ss[192 + row];
        float q = Sq[row] + Sq[64 + row] + Sq[128 + row] + Sq[192 + row];
        float mean = s * (1.0f / 256.0f);
        float var  = q * (1.0f / 256.0f) - mean * mean;
        float rinv = rsqrtf(var + 1e-5f);
        #pragma unroll
        for (int j = 0; j < 4; ++j) {
            acc[i][j][0] = (acc[i][j][0] - mean) * rinv * scj[j].x + bbj[j].x;
            acc[i][j][1] = (acc[i][j][1] - mean) * rinv * scj[j].y + bbj[j].y;
            acc[i][j][2] = (acc[i][j][2] - mean) * rinv * scj[j].z + bbj[j].z;
            acc[i][j][3] = (acc[i][j][3] - mean) * rinv * scj[j].w + bbj[j].w;
        }
    }

    // stores: Xh fp16 8B; Xb direct k-chunk 8B packs.
    #pragma unroll
    for (int i = 0; i < 4; ++i) {
        int m = m0 + i * 16 + l15;
        size_t gf = (size_t)m * DM + wn + quad * 4;
        size_t m8 = (size_t)m * 8;
        #pragma unroll
        for (int j = 0; j < 4; ++j) {
            f16x4 oh = { (_Float16)acc[i][j][0], (_Float16)acc[i][j][1],
                         (_Float16)acc[i][j][2], (_Float16)acc[i][j][3] };
            *(f16x4*)(Xh + gf + j * 16) = oh;
            int nb = wn + j * 16 + quad * 4;
            uint2 ob;
            ob.x = f2bf(acc[i][j][0]) | ((unsigned)f2bf(acc[i][j][1]) << 16);
            ob.y = f2bf(acc[i][j][2]) | ((unsigned)f2bf(acc[i][j][3]) << 16);
            *(uint2*)(Xb + ((size_t)(nb >> 3)) * M8 + m8 + (nb & 7)) = ob;
        }
    }
}

// ------------------------------------------------------- MFMA attention ----
// QKV/ATT in k-chunk-major layout. One wave per (window, head).
// R12: LDS compacted 22016 -> 13824 B. Layout: VT[0,4608) Qs[4608,8704)
// Ks[8704,12800); Ps/Po overlay [4608,13824) -- Qs/Ks are dead (consumed
// into aq/bk registers) before Ps is written; same-wave DS ops execute in
// program order and the lgkmcnt(0) fences cover the RAW edges.
__global__ __launch_bounds__(64) void attn_mfma_kernel(
    const unsigned short* __restrict__ QKV, unsigned short* __restrict__ ATT)
{
    __shared__ __align__(16) char smem[13824];
    unsigned short* VT = (unsigned short*)smem;            // [d][t] 32 x pitch72
    unsigned short* Qs = (unsigned short*)(smem + 4608);   // [dc][t][8] 4x64x8
    unsigned short* Ks = (unsigned short*)(smem + 8704);   // [dc][t][8]
    unsigned short* Ps = (unsigned short*)(smem + 4608);   // [q][k] 64 x pitch72
    float*          Po = (float*)(smem + 4608);            // [q][d] 64 x pitch36

    const int wg = blockIdx.x, h = blockIdx.y;
    const int base = wg * WIN;
    const int lane = threadIdx.x;
    const int l15 = lane & 15, quad = lane >> 4;
    const float scale = 0.17677669529663687f;   // 1/sqrt(32)

    // stage Q,K: chunk-major source -> contiguous 1KB per DMA instruction
    #pragma unroll
    for (int dc = 0; dc < 4; ++dc) {
        GLD_LDS16(QKV + ((size_t)(h * 4 + dc)) * M8 + (size_t)(base + lane) * 8,
                  Qs + dc * 512 + (size_t)lane * 8);
        GLD_LDS16(QKV + ((size_t)(32 + h * 4 + dc)) * M8 + (size_t)(base + lane) * 8,
                  Ks + dc * 512 + (size_t)lane * 8);
    }
    u16x8 vv[4];
    #pragma unroll
    for (int cc = 0; cc < 4; ++cc)
        vv[cc] = *(const u16x8*)(QKV + ((size_t)(64 + h * 4 + cc)) * M8 +
                                 (size_t)(base + lane) * 8);
    #pragma unroll
    for (int cc = 0; cc < 4; ++cc)
        #pragma unroll
        for (int e = 0; e < 8; ++e)
            VT[(cc * 8 + e) * 72 + lane] = vv[cc][e];
    __syncthreads();   // drains vmcnt (DMA) + lgkm (VT writes)

    const f32x4 zero4 = {0.f, 0.f, 0.f, 0.f};
    bf16x8 aq[4], bk[4];
    #pragma unroll
    for (int i = 0; i < 4; ++i)
        aq[i] = *(const bf16x8*)(Qs + quad * 512 + (i * 16 + l15) * 8);
    #pragma unroll
    for (int j = 0; j < 4; ++j)
        bk[j] = *(const bf16x8*)(Ks + quad * 512 + (j * 16 + l15) * 8);
    f32x4 S[4][4];
    #pragma unroll
    for (int i = 0; i < 4; ++i)
        #pragma unroll
        for (int j = 0; j < 4; ++j)
            S[i][j] = __builtin_amdgcn_mfma_f32_16x16x32_bf16(aq[i], bk[j], zero4, 0, 0, 0);

    float mx[4][4], sum[4][4];
    #pragma unroll
    for (int i = 0; i < 4; ++i)
        #pragma unroll
        for (int r = 0; r < 4; ++r) {
            float m0 = -1e30f;
            #pragma unroll
            for (int j = 0; j < 4; ++j) {
                S[i][j][r] *= scale;
                m0 = fmaxf(m0, S[i][j][r]);
            }
            mx[i][r] = m0;
        }
    #pragma unroll
    for (int off = 1; off < 16; off <<= 1)
        #pragma unroll
        for (int i = 0; i < 4; ++i)
            #pragma unroll
            for (int r = 0; r < 4; ++r)
                mx[i][r] = fmaxf(mx[i][r], __shfl_xor(mx[i][r], off));
    #pragma unroll
    for (int i = 0; i < 4; ++i)
        #pragma unroll
        for (int r = 0; r < 4; ++r) {
            float s0 = 0.f;
            #pragma unroll
            for (int j = 0; j < 4; ++j) {
                float e = __expf(S[i][j][r] - mx[i][r]);
                S[i][j][r] = e;
                s0 += e;
            }
            sum[i][r] = s0;
        }
    #pragma unroll
    for (int off = 1; off < 16; off <<= 1)
        #pragma unroll
        for (int i = 0; i < 4; ++i)
            #pragma unroll
            for (int r = 0; r < 4; ++r)
                sum[i][r] += __shfl_xor(sum[i][r], off);

    #pragma unroll
    for (int i = 0; i < 4; ++i)
        #pragma unroll
        for (int r = 0; r < 4; ++r) {
            float inv = 1.0f / sum[i][r];
            #pragma unroll
            for (int j = 0; j < 4; ++j)
                Ps[(i * 16 + quad * 4 + r) * 72 + j * 16 + l15] =
                    f2bf(S[i][j][r] * inv);
        }
    asm volatile("s_waitcnt lgkmcnt(0)" ::: "memory");

    bf16x8 ap0[4], ap1[4], bv0[2], bv1[2];
    #pragma unroll
    for (int i = 0; i < 4; ++i) {
        ap0[i] = *(const bf16x8*)(Ps + (i * 16 + l15) * 72 + quad * 8);
        ap1[i] = *(const bf16x8*)(Ps + (i * 16 + l15) * 72 + 32 + quad * 8);
    }
    #pragma unroll
    for (int jd = 0; jd < 2; ++jd) {
        bv0[jd] = *(const bf16x8*)(VT + (jd * 16 + l15) * 72 + quad * 8);
        bv1[jd] = *(const bf16x8*)(VT + (jd * 16 + l15) * 72 + 32 + quad * 8);
    }
    f32x4 O[4][2];
    #pragma unroll
    for (int i = 0; i < 4; ++i)
        #pragma unroll
        for (int jd = 0; jd < 2; ++jd) {
            f32x4 t = __builtin_amdgcn_mfma_f32_16x16x32_bf16(ap0[i], bv0[jd], zero4, 0, 0, 0);
            O[i][jd] = __builtin_amdgcn_mfma_f32_16x16x32_bf16(ap1[i], bv1[jd], t, 0, 0, 0);
        }
    asm volatile("s_waitcnt lgkmcnt(0)" ::: "memory");

    #pragma unroll
    for (int i = 0; i < 4; ++i)
        #pragma unroll
        for (int jd = 0; jd < 2; ++jd)
            #pragma unroll
            for (int r = 0; r < 4; ++r)
                Po[(i * 16 + quad * 4 + r) * 36 + jd * 16 + l15] = O[i][jd][r];
    asm volatile("s_waitcnt lgkmcnt(0)" ::: "memory");

    // ATT out: k-chunk-major, contiguous 1KB per chunk store
    #pragma unroll
    for (int g = 0; g < 4; ++g) {
        f32x4 t0 = *(const f32x4*)(Po + lane * 36 + g * 8);
        f32x4 t1 = *(const f32x4*)(Po + lane * 36 + g * 8 + 4);
        uint4 w;
        w.x = f2bf(t0[0]) | ((unsigned)f2bf(t0[1]) << 16);
        w.y = f2bf(t0[2]) | ((unsigned)f2bf(t0[3]) << 16);
        w.z = f2bf(t1[0]) | ((unsigned)f2bf(t1[1]) << 16);
        w.w = f2bf(t1[2]) | ((unsigned)f2bf(t1[3]) << 16);
        *(uint4*)(ATT + ((size_t)(h * 4 + g)) * M8 + (size_t)(base + lane) * 8) = w;
    }
}

// ---------------------------------------------- final LN + transpose out ---
// single pass: tile 64 tokens x 256 ch in LDS (pitch 257), stats inline.
// reads fp16 trunk, writes fp32 output.
__global__ __launch_bounds__(256) void out_ln_kernel(
    const _Float16* __restrict__ Xh, const float* __restrict__ sc,
    const float* __restrict__ bi, float* __restrict__ out)
{
    __shared__ float tile[64][257];
    __shared__ float mean_s[64], rinv_s[64];
    int b = blockIdx.y, l0 = blockIdx.x * 64;
    int tid = threadIdx.x, wave = tid >> 6, lane = tid & 63;
    int c = lane * 4;
    #pragma unroll
    for (int it = 0; it < 16; ++it) {
        int tl = wave * 16 + it;
        f16x4 h = *(const f16x4*)(Xh + ((size_t)(b * LSEQ + l0 + tl)) * DM + c);
        float vx = (float)h[0], vy = (float)h[1], vz = (float)h[2], vw = (float)h[3];
        tile[tl][c + 0] = vx; tile[tl][c + 1] = vy;
        tile[tl][c + 2] = vz; tile[tl][c + 3] = vw;
        float sm = vx + vy + vz + vw;
        float sq = vx * vx + vy * vy + vz * vz + vw * vw;
        #pragma unroll
        for (int off = 32; off > 0; off >>= 1) {
            sm += __shfl_down(sm, off);
            sq += __shfl_down(sq, off);
        }
        if (lane == 0) {
            float mean = sm * (1.0f / 256.0f);
            float var  = sq * (1.0f / 256.0f) - mean * mean;
            mean_s[tl] = mean;
            rinv_s[tl] = rsqrtf(var + 1e-5f);
        }
    }
    __syncthreads();
    int lout = tid & 63, crow = tid >> 6;
    #pragma unroll
    for (int ct = 0; ct < 4; ++ct) {
        int c0 = ct * 64;
        #pragma unroll
        for (int it = 0; it < 16; ++it) {
            int cc = c0 + crow + it * 4;
            float v = tile[lout][cc];
            out[((size_t)(b * DM + cc)) * LSEQ + l0 + lout] =
                (v - mean_s[lout]) * rinv_s[lout] * sc[cc] + bi[cc];
        }
    }
}

// ----------------------------------------------------------------- driver --
extern "C" void kernel_launch(void* const* d_in, const int* in_sizes, int n_in,
                              void* d_out, int out_size, void* d_ws, size_t ws_size,
                              hipStream_t stream)
{
    const float* F   = (const float*)d_in[0];
    const float* Wi  = (const float*)d_in[1];
    const float* Bi  = (const float*)d_in[2];
    const float* Wo  = (const float*)d_in[3];
    const float* Bo  = (const float*)d_in[4];
    const float* W1  = (const float*)d_in[5];
    const float* B1  = (const float*)d_in[6];
    const float* W2  = (const float*)d_in[7];
    const float* B2  = (const float*)d_in[8];
    const float* L1s = (const float*)d_in[9];
    const float* L1b = (const float*)d_in[10];
    const float* L2s = (const float*)d_in[11];
    const float* L2b = (const float*)d_in[12];
    const float* Fs  = (const float*)d_in[13];
    const float* Fb  = (const float*)d_in[14];

    char* w = (char*)d_ws;
    _Float16*       Xh   = (_Float16*)w;                           // 16.8 MB
    unsigned short* QKVb = (unsigned short*)(w + 33554432);        // 50 MB
    unsigned short* Hb   = (unsigned short*)(w + 83886080);        // 67 MB
    unsigned short* Xb   = (unsigned short*)(w + 150994944);       // 16.8 MB
    unsigned short* ATTb = (unsigned short*)(w + 167772160);       // 16.8 MB
    unsigned short* WB   = (unsigned short*)(w + 184549376);       // 4.7 MB
    float*          PE   = (float*)(w + 189267968);                // 1 MB
    unsigned short* Wib  = WB;
    unsigned short* Wob  = WB + 589824;
    unsigned short* W1b  = WB + 786432;
    unsigned short* W2b  = WB + 1572864;

    cvt_kernel<<<(3 * 768 * 32 + 255) / 256, 256, 0, stream>>>(Wi, Wib, 768, 256, 3);
    cvt_kernel<<<(3 * 256 * 32 + 255) / 256, 256, 0, stream>>>(Wo, Wob, 256, 256, 3);
    cvt_kernel<<<(3 * 1024 * 32 + 255) / 256, 256, 0, stream>>>(W1, W1b, 1024, 256, 3);
    cvt_kernel<<<(3 * 256 * 128 + 255) / 256, 256, 0, stream>>>(W2, W2b, 256, 1024, 3);
    pe_kernel<<<LSEQ, 256, 0, stream>>>(PE);
    embed_kernel<<<dim3(DM / 64, LSEQ / 64, BSZ), 256, 0, stream>>>(F, PE, Xh, Xb);

    for (int i = 0; i < 3; ++i) {
        // QKV = X @ Wi^T + bi -> QKVb (k-chunk bf16)
        gemm_mfma_kernel<<<dim3(MTOK / 128, 768 / 128), 256, 0, stream>>>(
            Xb, Wib + (size_t)i * 196608, Bi + i * 768, QKVb, MTOK, 768, DM, 0);
        // windowed MHA -> ATTb
        attn_mfma_kernel<<<dim3(BSZ * (LSEQ / WIN), NHEAD), 64, 0, stream>>>(QKVb, ATTb);
        // X = LN1( ATT @ Wo^T + bo + X ) -> Xh + Xb
        gemm_ln_kernel<<<MTOK / 64, 256, 0, stream>>>(
            ATTb, Wob + (size_t)i * 65536, Bo + i * DM, Xh,
            L1s + i * DM, L1b + i * DM, Xh, Xb, DM);
        // H = GELU(X @ W1^T + b1) -> Hb
        gemm_mfma_kernel<<<dim3(MTOK / 128, DFF / 128), 256, 0, stream>>>(
            Xb, W1b + (size_t)i * 262144, B1 + i * DFF, Hb, MTOK, DFF, DM, 1);
        // X = LN2( H @ W2^T + b2 + X ) -> Xh + Xb
        gemm_ln_kernel<<<MTOK / 64, 256, 0, stream>>>(
            Hb, W2b + (size_t)i * 262144, B2 + i * DM, Xh,
            L2s + i * DM, L2b + i * DM, Xh, Xb, DFF);
    }

    out_ln_kernel<<<dim3(LSEQ / 64, BSZ), 256, 0, stream>>>(
        Xh, Fs, Fb, (float*)d_out);
}